// Round 22
// baseline (395.698 us; speedup 1.0000x reference)
//
#include <hip/hip_runtime.h>

typedef _Float16 half8 __attribute__((ext_vector_type(8)));
typedef _Float16 half4 __attribute__((ext_vector_type(4)));
typedef float f32x4 __attribute__((ext_vector_type(4)));

#define MFMA16(a,b,c) __builtin_amdgcn_mfma_f32_16x16x32_f16(a,b,c,0,0,0)
#define GLOAD16(g, l) __builtin_amdgcn_global_load_lds( \
  (const __attribute__((address_space(1))) void*)(g), \
  (__attribute__((address_space(3))) void*)(l), 16, 0, 0)
#define SCHEDB() __builtin_amdgcn_sched_barrier(0)

static constexpr int NW     = 1568;     // 8*14*14 windows
static constexpr int MROWSQ = 76832;    // NW*49
static constexpr int MPADQ  = 76928;    // 601*128
static constexpr int MROWKV = 39200;    // NW*25
static constexpr int MPADKV = 39296;    // 307*128
static constexpr float LOG2E = 1.4426950408889634f;

__device__ __forceinline__ half8 h8z(){
  half8 z = {(_Float16)0,(_Float16)0,(_Float16)0,(_Float16)0,
             (_Float16)0,(_Float16)0,(_Float16)0,(_Float16)0};
  return z;
}

// ---- prep: weights fp32 -> fp16 (Wq pre-scaled by DH^-0.5 * log2e) ----
__global__ void k_prep_w(const float* __restrict__ a, const float* __restrict__ b,
                         const float* __restrict__ c,
                         _Float16* __restrict__ ah, _Float16* __restrict__ bh,
                         _Float16* __restrict__ ch){
  int i = blockIdx.x*256 + threadIdx.x;
  if(i < 262144) ah[i] = (_Float16)(a[i]*(0.25f*LOG2E));
  int j = i - 262144;
  if(j >= 0 && j < 524288) bh[j] = (_Float16)b[j];
  int k = i - 786432;
  if(k >= 0 && k < 262144) ch[k] = (_Float16)c[k];
}

// ---- prep: bias in swapped-QK lane layout, pre-scaled by log2e ----
__global__ void k_prep_bias(const float* __restrict__ rel, float* __restrict__ biasT){
  int t = blockIdx.x*256 + threadIdx.x;   // 32h * 64i * 32slots = 65536
  if(t >= 65536) return;
  int h = t >> 11;
  int r = t & 2047;
  int i = r >> 5, slotk = r & 31;
  int kg = slotk >> 3, idx = slotk & 7;
  int j = (idx < 4) ? (kg*4 + idx) : (16 + kg*4 + idx - 4);
  float v = 0.f;
  if(j >= 25) v = -1e30f;
  else if(i < 49){
    int qi = i/7, qj = i%7;
    int c = j + 24, ki = c/7, kj = c%7;
    v = rel[((qi-ki+6)*13 + (qj-kj+6))*32 + h];
  }
  biasT[t] = v*LOG2E;
}

// ---- LN(x) -> xn : one WAVE per token row, fully parallel streaming ----
__global__ __launch_bounds__(256) void k_ln(const float* __restrict__ x,
    const float* __restrict__ gamma, const float* __restrict__ beta,
    _Float16* __restrict__ xn){
  const int t = threadIdx.x, lane = t & 63, wv = t >> 6;
  const int row = blockIdx.x*4 + wv;
  if(row >= MROWSQ) return;
  float4 g0 = *(const float4*)(gamma + lane*8);
  float4 g1 = *(const float4*)(gamma + lane*8 + 4);
  float4 b0 = *(const float4*)(beta  + lane*8);
  float4 b1 = *(const float4*)(beta  + lane*8 + 4);
  const float* r = x + (size_t)row*512 + lane*8;
  float4 v0 = *(const float4*)r;
  float4 v1 = *(const float4*)(r+4);
  float v[8] = {v0.x,v0.y,v0.z,v0.w,v1.x,v1.y,v1.z,v1.w};
  float gf[8] = {g0.x,g0.y,g0.z,g0.w,g1.x,g1.y,g1.z,g1.w};
  float bf[8] = {b0.x,b0.y,b0.z,b0.w,b1.x,b1.y,b1.z,b1.w};
  float s = 0.f, sq = 0.f;
  #pragma unroll
  for(int j=0;j<8;j++){ s += v[j]; sq += v[j]*v[j]; }
  #pragma unroll
  for(int o=32;o>=1;o>>=1){ s += __shfl_xor(s,o); sq += __shfl_xor(sq,o); }
  float mean = s*(1.f/512.f);
  float rstd = rsqrtf(sq*(1.f/512.f) - mean*mean + 1e-5f);
  half8 nh;
  #pragma unroll
  for(int j=0;j<8;j++) nh[j] = (_Float16)((v[j]-mean)*rstd*gf[j] + bf[j]);
  *(half8*)(xn + (size_t)row*512 + lane*8) = nh;
}

// ---- pool 3x3 over xn rows -> LN -> xkv : one WAVE per pooled row ----
__global__ __launch_bounds__(256) void k_pool(const _Float16* __restrict__ xn,
    const float* __restrict__ gamma, const float* __restrict__ beta,
    _Float16* __restrict__ xkv){
  const int t = threadIdx.x, lane = t & 63, wv = t >> 6;
  const int r = blockIdx.x*4 + wv;
  if(r >= MROWKV) return;
  const int w = r/25, p = r - w*25;
  const int pi = p/5, pj = p - (p/5)*5;
  float4 g0 = *(const float4*)(gamma + lane*8);
  float4 g1 = *(const float4*)(gamma + lane*8 + 4);
  float4 b0 = *(const float4*)(beta  + lane*8);
  float4 b1 = *(const float4*)(beta  + lane*8 + 4);
  float gf[8] = {g0.x,g0.y,g0.z,g0.w,g1.x,g1.y,g1.z,g1.w};
  float bf[8] = {b0.x,b0.y,b0.z,b0.w,b1.x,b1.y,b1.z,b1.w};
  const _Float16* xnw = xn + (size_t)w*49*512;
  float acc[8] = {0,0,0,0,0,0,0,0};
  #pragma unroll
  for(int a=0;a<3;a++)
    #pragma unroll
    for(int bb=0;bb<3;bb++){
      half8 rv = *(const half8*)(xnw + (size_t)((pi+a)*7 + (pj+bb))*512 + lane*8);
      #pragma unroll
      for(int j=0;j<8;j++) acc[j] += (float)rv[j];
    }
  float s = 0.f, sq = 0.f;
  #pragma unroll
  for(int j=0;j<8;j++){ acc[j] *= (1.f/9.f); s += acc[j]; sq += acc[j]*acc[j]; }
  #pragma unroll
  for(int o=32;o>=1;o>>=1){ s += __shfl_xor(s,o); sq += __shfl_xor(sq,o); }
  float mean = s*(1.f/512.f);
  float rstd = rsqrtf(sq*(1.f/512.f) - mean*mean + 1e-5f);
  half8 nh;
  #pragma unroll
  for(int j=0;j<8;j++) nh[j] = (_Float16)((acc[j]-mean)*rstd*gf[j] + bf[j]);
  *(half8*)(xkv + (size_t)r*512 + lane*8) = nh;
}

// ---- C(M x N) = A(M x 512) @ W(N x 512)^T, 128x128 tile, 4 waves 2x2 ----
// T3+T4: 3-buffer counted-vmcnt pipeline, every s_barrier fenced both sides.
// + T2 both-sides XOR swizzle. 1-D grid, bijective XCD remap.
template<int MODE>
__global__ __launch_bounds__(256) void k_gemm(const _Float16* __restrict__ A,
    const _Float16* __restrict__ Bw, _Float16* __restrict__ oh,
    float* __restrict__ of, int ldc, int ntn, int nwg){
  __shared__ __align__(16) _Float16 As[3][128*32];   // 3 x 8 KB
  __shared__ __align__(16) _Float16 Bs[3][128*32];
  const int orig = blockIdx.x;
  const int xcd = orig & 7, slot = orig >> 3;
  const int q8 = nwg >> 3, r8 = nwg & 7;
  const int base = (xcd < r8) ? xcd*(q8+1) : r8*(q8+1) + (xcd-r8)*q8;
  const int lin = base + slot;
  const int m0 = (lin / ntn) * 128, n0 = (lin % ntn) * 128;
  const int t = threadIdx.x, lane = t & 63;
  const int wid = t >> 6, wm = (wid>>1)*64, wn = (wid&1)*64;
  const int lr = lane & 15, kg = lane >> 4;
  const _Float16* Ab = A  + (size_t)m0*512;
  const _Float16* Bb = Bw + (size_t)n0*512;
  const int foff0 = wid*64, foff1 = 256 + wid*64;
  const int f0 = foff0 + lane, f1 = foff1 + lane;
  const int r0 = f0 >> 2, r1 = f1 >> 2;
  const size_t ga0 = (size_t)r0*512 + ((f0&3) ^ ((r0>>1)&3))*8;
  const size_t ga1 = (size_t)r1*512 + ((f1&3) ^ ((r1>>1)&3))*8;
  const int swz = (lr>>1) & 3;           // read-side XOR (row bits 1-2)

  auto STAGE = [&](int buf, int kt){
    const int k0 = kt*32;
    GLOAD16(Ab + ga0 + k0, &As[buf][foff0*8]);
    GLOAD16(Bb + ga0 + k0, &Bs[buf][foff0*8]);
    GLOAD16(Ab + ga1 + k0, &As[buf][foff1*8]);
    GLOAD16(Bb + ga1 + k0, &Bs[buf][foff1*8]);
  };
  STAGE(0, 0);
  STAGE(1, 1);                            // 8 loads in flight

  f32x4 acc[4][4] = {};
  int buf = 0;
  for(int kt = 0; kt < 16; ++kt){
    if(kt + 2 < 16){
      int nb = buf + 2; if(nb >= 3) nb -= 3;
      STAGE(nb, kt + 2);                  // 12 in flight
    }
    if(kt < 14)       asm volatile("s_waitcnt vmcnt(8)" ::: "memory");
    else if(kt == 14) asm volatile("s_waitcnt vmcnt(4)" ::: "memory");
    else              asm volatile("s_waitcnt vmcnt(0)" ::: "memory");
    SCHEDB();
    __builtin_amdgcn_s_barrier();         // all waves' tile-kt loads landed
    SCHEDB();
    const _Float16* Ac = As[buf];
    const _Float16* Bc = Bs[buf];
    half8 af[4], bf[4];
    #pragma unroll
    for(int mt=0;mt<4;mt++)
      af[mt] = *(const half8*)&Ac[(wm + mt*16 + lr)*32 + (kg ^ swz)*8];
    #pragma unroll
    for(int nt=0;nt<4;nt++)
      bf[nt] = *(const half8*)&Bc[(wn + nt*16 + lr)*32 + (kg ^ swz)*8];
    #pragma unroll
    for(int mt=0;mt<4;mt++)
      #pragma unroll
      for(int nt=0;nt<4;nt++)
        acc[mt][nt] = MFMA16(af[mt], bf[nt], acc[mt][nt]);
    SCHEDB();
    __builtin_amdgcn_s_barrier();         // reads done -> buf may be restaged
    SCHEDB();
    buf += 1; if(buf >= 3) buf -= 3;
  }
  #pragma unroll
  for(int mt=0;mt<4;mt++)
    #pragma unroll
    for(int nt=0;nt<4;nt++)
      #pragma unroll
      for(int r=0;r<4;r++){
        int row = m0 + wm + mt*16 + kg*4 + r;
        int col = n0 + wn + nt*16 + lr;
        float vv = acc[mt][nt][r];
        if(MODE == 0){
          oh[(size_t)row*ldc + col] = (_Float16)vv;
        } else {
          if(row < MROWSQ) of[(size_t)row*ldc + col] = vv;
        }
      }
}

// ---- repack kv (row-major M x 1024) -> K head-major [w][h][j][dh]
//      and V TRANSPOSED [w][h][dh][j_pad32] (pad zeroed) ----
__global__ __launch_bounds__(256) void k_repack(const _Float16* __restrict__ kvb,
    _Float16* __restrict__ kb, _Float16* __restrict__ vb){
  __shared__ uint2 s2[6400];              // 25 rows x 256 uint2 = 50 KB
  uint32_t* su = (uint32_t*)s2;
  const int w = blockIdx.x, t = threadIdx.x;
  const uint2* src = (const uint2*)(kvb + (size_t)w*25*1024);
  #pragma unroll
  for(int it=0; it<25; ++it){
    int U = it*256 + t;
    int j = U >> 8, u = U & 255;          // u = dh*16 + (h>>1)
    s2[j*256 + (u ^ (u>>4) ^ (j&15))] = src[U];
  }
  __syncthreads();
  _Float16* kdst = kb + (size_t)w*12800;
  // K: [h][j][dh], unchanged
  for(int it=0; it<7; ++it){
    int q = it*256 + t;                   // half8 index into [32h][25j][2half]
    if(q < 1600){
      int h = q/50, rem = q%50, j = rem>>1, half = rem&1;
      half8 k8;
      #pragma unroll
      for(int jj=0;jj<8;jj++){
        int dh = half*8 + jj;
        int slot = j*256 + ((dh*16 + (h>>1)) ^ dh ^ (j&15));
        uint32_t val = su[slot*2 + (h&1)];
        k8[jj] = ((_Float16*)&val)[0];    // c=0 -> K
      }
      *(half8*)(kdst + q*8) = k8;
    }
  }
  // V^T: [h][dh][j32], j>=25 zero pad
  _Float16* vtdst = vb + (size_t)w*16384;
  for(int it=0; it<8; ++it){
    int u = it*256 + t;                   // half8 index into [32h][16dh][4jq]
    int h = u >> 6, rem = u & 63;
    int dh = rem >> 2, jq = rem & 3;
    half8 v8 = h8z();
    #pragma unroll
    for(int jj=0;jj<8;jj++){
      int j = jq*8 + jj;
      if(j < 25){
        int slot = j*256 + ((dh*16 + (h>>1)) ^ dh ^ (j&15));
        uint32_t val = su[slot*2 + (h&1)];
        v8[jj] = ((_Float16*)&val)[1];    // c=1 -> V
      }
    }
    *(half8*)(vtdst + u*8) = v8;
  }
}

// ---- attention: swapped QK^T (S^T = K x Q), softmax fully in-register ----
// 1-D grid (6272) with bijective XCD remap over WINDOW-MAJOR order: the 4
// blocks sharing a window's Q/K/V run consecutively on the SAME XCD -> the
// window working set (~100 KB) is fetched into that L2 once (T1). Wave wv
// handles heads hA = hi*4+wv, hB = hA+16. V^T frags. No LDS, no barriers.
__global__ __launch_bounds__(256) void k_attn(const _Float16* __restrict__ q,
    const _Float16* __restrict__ kb, const _Float16* __restrict__ vb,
    const float* __restrict__ biasT, _Float16* __restrict__ ao){
  const int orig = blockIdx.x;            // 0..6271 (6272 = 8*784)
  const int lin = (orig & 7)*784 + (orig >> 3);   // bijective XCD remap
  const int w = lin >> 2, hi = lin & 3;   // window-major: 4 blocks/window adj
  const int t = threadIdx.x;
  const int lane = t & 63, wv = t >> 6;
  const int lr = lane & 15, kg = lane >> 4;
  const size_t qbase = ((size_t)w*49)*512;
  const int hA = hi*4 + wv;              // 0..15
  const size_t kvA = (((size_t)w*32 + hA)*25)*16;
  const size_t kvB = kvA + 6400;         // +16 heads (K layout)
  half8 kA0=h8z(), kA1=h8z(), kB0=h8z(), kB1=h8z();
  if(kg < 2){
    kA0 = *(const half8*)(kb + kvA + lr*16 + kg*8);
    kB0 = *(const half8*)(kb + kvB + lr*16 + kg*8);
    if(lr < 9){
      kA1 = *(const half8*)(kb + kvA + (16+lr)*16 + kg*8);
      kB1 = *(const half8*)(kb + kvB + (16+lr)*16 + kg*8);
    }
  }
  half8 qA[4], qB[4];
  #pragma unroll
  for(int qt=0;qt<4;qt++){
    if(kg < 2){
      const _Float16* p = q + qbase + (size_t)(qt*16+lr)*512 + hA*16 + kg*8;
      qA[qt] = *(const half8*)p;
      qB[qt] = *(const half8*)(p + 256);
    } else { qA[qt] = h8z(); qB[qt] = h8z(); }
  }
  // V frags from V^T [h][dh=lr][j32]: keys {kg*4..+3} and {16+kg*4..+3}
  half8 vA, vB;
  {
    const _Float16* vtA = vb + ((size_t)w*32 + hA)*512 + lr*32 + kg*4;
    const _Float16* vtB = vtA + 16*512;   // +16 heads (V^T layout)
    half4 a0 = *(const half4*)vtA;
    half4 a1 = *(const half4*)(vtA + 16);
    half4 b0 = *(const half4*)vtB;
    half4 b1 = *(const half4*)(vtB + 16);
    vA = __builtin_shufflevector(a0, a1, 0,1,2,3,4,5,6,7);
    vB = __builtin_shufflevector(b0, b1, 0,1,2,3,4,5,6,7);
  }
  const float4* btA = (const float4*)(biasT + (size_t)hA*2048);
  const float4* btB = (const float4*)(biasT + (size_t)(hA+16)*2048);
  #pragma unroll
  for(int qt=0;qt<4;qt++){
    f32x4 sA0={}, sA1={}, sB0={}, sB1={};
    sA0 = MFMA16(kA0, qA[qt], sA0);      // S^T[key][query]
    sA1 = MFMA16(kA1, qA[qt], sA1);
    sB0 = MFMA16(kB0, qB[qt], sB0);
    sB1 = MFMA16(kB1, qB[qt], sB1);
    const int i = qt*16 + lr;            // this lane's query
    const int bidx = i*8 + kg*2;         // float4 units
    float4 bA0 = btA[bidx], bA1 = btA[bidx+1];
    float4 bB0 = btB[bidx], bB1 = btB[bidx+1];
    float a[8], b[8];
    a[0]=sA0[0]+bA0.x; a[1]=sA0[1]+bA0.y; a[2]=sA0[2]+bA0.z; a[3]=sA0[3]+bA0.w;
    a[4]=sA1[0]+bA1.x; a[5]=sA1[1]+bA1.y; a[6]=sA1[2]+bA1.z; a[7]=sA1[3]+bA1.w;
    b[0]=sB0[0]+bB0.x; b[1]=sB0[1]+bB0.y; b[2]=sB0[2]+bB0.z; b[3]=sB0[3]+bB0.w;
    b[4]=sB1[0]+bB1.x; b[5]=sB1[1]+bB1.y; b[6]=sB1[2]+bB1.z; b[7]=sB1[3]+bB1.w;
    float mA = a[0], mB = b[0];
    #pragma unroll
    for(int j=1;j<8;j++){ mA = fmaxf(mA, a[j]); mB = fmaxf(mB, b[j]); }
    mA = fmaxf(mA, __shfl_xor(mA,16)); mB = fmaxf(mB, __shfl_xor(mB,16));
    mA = fmaxf(mA, __shfl_xor(mA,32)); mB = fmaxf(mB, __shfl_xor(mB,32));
    float sumA = 0.f, sumB = 0.f;
    #pragma unroll
    for(int j=0;j<8;j++){
      a[j] = exp2f(a[j]-mA); sumA += a[j];
      b[j] = exp2f(b[j]-mB); sumB += b[j];
    }
    sumA += __shfl_xor(sumA,16); sumB += __shfl_xor(sumB,16);
    sumA += __shfl_xor(sumA,32); sumB += __shfl_xor(sumB,32);
    float invA = 1.f/sumA, invB = 1.f/sumB;
    half8 pA, pB;
    #pragma unroll
    for(int j=0;j<8;j++){
      pA[j] = (_Float16)(a[j]*invA);
      pB[j] = (_Float16)(b[j]*invB);
    }
    f32x4 oA={}, oB={};
    oA = MFMA16(pA, vA, oA);             // O[query][dh]
    oB = MFMA16(pB, vB, oB);
    #pragma unroll
    for(int r=0;r<4;r++){
      int qi2 = qt*16 + kg*4 + r;
      if(qi2 < 49){
        _Float16* dst = ao + qbase + (size_t)qi2*512 + hA*16 + lr;
        dst[0]   = (_Float16)oA[r];
        dst[256] = (_Float16)oB[r];
      }
    }
  }
}

extern "C" void kernel_launch(void* const* d_in, const int* in_sizes, int n_in,
                              void* d_out, int out_size, void* d_ws, size_t ws_size,
                              hipStream_t stream){
  (void)in_sizes; (void)n_in; (void)out_size; (void)ws_size;
  const float* x    = (const float*)d_in[0];
  const float* gam  = (const float*)d_in[1];
  const float* bet  = (const float*)d_in[2];
  const float* Wq   = (const float*)d_in[3];
  const float* Wkv  = (const float*)d_in[4];
  const float* Wout = (const float*)d_in[5];
  const float* rel  = (const float*)d_in[6];
  float* out = (float*)d_out;

  char* ws = (char*)d_ws;
  size_t off = 0;
  auto alloc = [&](size_t n){ char* p = ws + off; off += (n + 1023) & ~(size_t)1023; return p; };
  _Float16* xn    = (_Float16*)alloc((size_t)MPADQ*512*2);      // also reused as attn_out
  _Float16* xkv   = (_Float16*)alloc((size_t)MPADKV*512*2);
  _Float16* kvb   = (_Float16*)alloc((size_t)MPADKV*1024*2);    // later reused as qb
  _Float16* kbuf  = (_Float16*)alloc((size_t)NW*32*25*16*2);
  _Float16* vbuf  = (_Float16*)alloc((size_t)NW*32*16*32*2);    // V^T, j padded to 32
  _Float16* wqh   = (_Float16*)alloc((size_t)262144*2);
  _Float16* wkvh  = (_Float16*)alloc((size_t)524288*2);
  _Float16* wouth = (_Float16*)alloc((size_t)262144*2);
  float*    biasT = (float*)   alloc((size_t)65536*4);          // [32][64][4][8]
  _Float16* qb    = kvb;   // alias: kvb dead after k_repack, qb written after

  k_prep_w   <<<dim3(4096), 256, 0, stream>>>(Wq, Wkv, Wout, wqh, wkvh, wouth);
  k_prep_bias<<<dim3(256),  256, 0, stream>>>(rel, biasT);
  k_ln       <<<dim3(19208),256, 0, stream>>>(x, gam, bet, xn);
  k_pool     <<<dim3(9800), 256, 0, stream>>>(xn, gam, bet, xkv);
  k_gemm<0>  <<<dim3(2456), 256, 0, stream>>>(xkv, wkvh, kvb, nullptr, 1024, 8, 2456);
  k_repack   <<<dim3(NW),   256, 0, stream>>>(kvb, kbuf, vbuf);
  k_gemm<0>  <<<dim3(2404), 256, 0, stream>>>(xn,  wqh,  qb,  nullptr,  512, 4, 2404);
  k_attn     <<<dim3(6272), 256, 0, stream>>>(qb, kbuf, vbuf, biasT, xn);
  k_gemm<1>  <<<dim3(2404), 256, 0, stream>>>(xn,  wouth, nullptr, out, 512, 4, 2404);
}

// Round 23
// 384.604 us; speedup vs baseline: 1.0288x; 1.0288x over previous
//
#include <hip/hip_runtime.h>

typedef _Float16 half8 __attribute__((ext_vector_type(8)));
typedef _Float16 half4 __attribute__((ext_vector_type(4)));
typedef float f32x4 __attribute__((ext_vector_type(4)));

#define MFMA16(a,b,c) __builtin_amdgcn_mfma_f32_16x16x32_f16(a,b,c,0,0,0)
#define GLOAD16(g, l) __builtin_amdgcn_global_load_lds( \
  (const __attribute__((address_space(1))) void*)(g), \
  (__attribute__((address_space(3))) void*)(l), 16, 0, 0)
#define SCHEDB() __builtin_amdgcn_sched_barrier(0)

static constexpr int NW     = 1568;     // 8*14*14 windows
static constexpr int MROWSQ = 76832;    // NW*49
static constexpr int MPADQ  = 76928;    // 601*128
static constexpr int MROWKV = 39200;    // NW*25
static constexpr int MPADKV = 39296;    // 307*128
static constexpr float LOG2E = 1.4426950408889634f;

__device__ __forceinline__ half8 h8z(){
  half8 z = {(_Float16)0,(_Float16)0,(_Float16)0,(_Float16)0,
             (_Float16)0,(_Float16)0,(_Float16)0,(_Float16)0};
  return z;
}

// ---- prep: weights fp32 -> fp16 (Wq pre-scaled by DH^-0.5 * log2e) ----
__global__ void k_prep_w(const float* __restrict__ a, const float* __restrict__ b,
                         const float* __restrict__ c,
                         _Float16* __restrict__ ah, _Float16* __restrict__ bh,
                         _Float16* __restrict__ ch){
  int i = blockIdx.x*256 + threadIdx.x;
  if(i < 262144) ah[i] = (_Float16)(a[i]*(0.25f*LOG2E));
  int j = i - 262144;
  if(j >= 0 && j < 524288) bh[j] = (_Float16)b[j];
  int k = i - 786432;
  if(k >= 0 && k < 262144) ch[k] = (_Float16)c[k];
}

// ---- prep: bias in swapped-QK lane layout, pre-scaled by log2e ----
__global__ void k_prep_bias(const float* __restrict__ rel, float* __restrict__ biasT){
  int t = blockIdx.x*256 + threadIdx.x;   // 32h * 64i * 32slots = 65536
  if(t >= 65536) return;
  int h = t >> 11;
  int r = t & 2047;
  int i = r >> 5, slotk = r & 31;
  int kg = slotk >> 3, idx = slotk & 7;
  int j = (idx < 4) ? (kg*4 + idx) : (16 + kg*4 + idx - 4);
  float v = 0.f;
  if(j >= 25) v = -1e30f;
  else if(i < 49){
    int qi = i/7, qj = i%7;
    int c = j + 24, ki = c/7, kj = c%7;
    v = rel[((qi-ki+6)*13 + (qj-kj+6))*32 + h];
  }
  biasT[t] = v*LOG2E;
}

// ---- LN(x) -> xn : one WAVE per token row, fully parallel streaming ----
__global__ __launch_bounds__(256) void k_ln(const float* __restrict__ x,
    const float* __restrict__ gamma, const float* __restrict__ beta,
    _Float16* __restrict__ xn){
  const int t = threadIdx.x, lane = t & 63, wv = t >> 6;
  const int row = blockIdx.x*4 + wv;
  if(row >= MROWSQ) return;
  float4 g0 = *(const float4*)(gamma + lane*8);
  float4 g1 = *(const float4*)(gamma + lane*8 + 4);
  float4 b0 = *(const float4*)(beta  + lane*8);
  float4 b1 = *(const float4*)(beta  + lane*8 + 4);
  const float* r = x + (size_t)row*512 + lane*8;
  float4 v0 = *(const float4*)r;
  float4 v1 = *(const float4*)(r+4);
  float v[8] = {v0.x,v0.y,v0.z,v0.w,v1.x,v1.y,v1.z,v1.w};
  float gf[8] = {g0.x,g0.y,g0.z,g0.w,g1.x,g1.y,g1.z,g1.w};
  float bf[8] = {b0.x,b0.y,b0.z,b0.w,b1.x,b1.y,b1.z,b1.w};
  float s = 0.f, sq = 0.f;
  #pragma unroll
  for(int j=0;j<8;j++){ s += v[j]; sq += v[j]*v[j]; }
  #pragma unroll
  for(int o=32;o>=1;o>>=1){ s += __shfl_xor(s,o); sq += __shfl_xor(sq,o); }
  float mean = s*(1.f/512.f);
  float rstd = rsqrtf(sq*(1.f/512.f) - mean*mean + 1e-5f);
  half8 nh;
  #pragma unroll
  for(int j=0;j<8;j++) nh[j] = (_Float16)((v[j]-mean)*rstd*gf[j] + bf[j]);
  *(half8*)(xn + (size_t)row*512 + lane*8) = nh;
}

// ---- pool 3x3 over xn rows -> LN -> xkv : one WAVE per pooled row ----
__global__ __launch_bounds__(256) void k_pool(const _Float16* __restrict__ xn,
    const float* __restrict__ gamma, const float* __restrict__ beta,
    _Float16* __restrict__ xkv){
  const int t = threadIdx.x, lane = t & 63, wv = t >> 6;
  const int r = blockIdx.x*4 + wv;
  if(r >= MROWKV) return;
  const int w = r/25, p = r - w*25;
  const int pi = p/5, pj = p - (p/5)*5;
  float4 g0 = *(const float4*)(gamma + lane*8);
  float4 g1 = *(const float4*)(gamma + lane*8 + 4);
  float4 b0 = *(const float4*)(beta  + lane*8);
  float4 b1 = *(const float4*)(beta  + lane*8 + 4);
  float gf[8] = {g0.x,g0.y,g0.z,g0.w,g1.x,g1.y,g1.z,g1.w};
  float bf[8] = {b0.x,b0.y,b0.z,b0.w,b1.x,b1.y,b1.z,b1.w};
  const _Float16* xnw = xn + (size_t)w*49*512;
  float acc[8] = {0,0,0,0,0,0,0,0};
  #pragma unroll
  for(int a=0;a<3;a++)
    #pragma unroll
    for(int bb=0;bb<3;bb++){
      half8 rv = *(const half8*)(xnw + (size_t)((pi+a)*7 + (pj+bb))*512 + lane*8);
      #pragma unroll
      for(int j=0;j<8;j++) acc[j] += (float)rv[j];
    }
  float s = 0.f, sq = 0.f;
  #pragma unroll
  for(int j=0;j<8;j++){ acc[j] *= (1.f/9.f); s += acc[j]; sq += acc[j]*acc[j]; }
  #pragma unroll
  for(int o=32;o>=1;o>>=1){ s += __shfl_xor(s,o); sq += __shfl_xor(sq,o); }
  float mean = s*(1.f/512.f);
  float rstd = rsqrtf(sq*(1.f/512.f) - mean*mean + 1e-5f);
  half8 nh;
  #pragma unroll
  for(int j=0;j<8;j++) nh[j] = (_Float16)((acc[j]-mean)*rstd*gf[j] + bf[j]);
  *(half8*)(xkv + (size_t)r*512 + lane*8) = nh;
}

// ---- C(M x N) = A(M x 512) @ W(N x 512)^T, 128x128 tile, 4 waves 2x2 ----
// T3+T4: 3-buffer counted-vmcnt pipeline, every s_barrier fenced both sides.
// + T2 both-sides XOR swizzle. 1-D grid, bijective XCD remap.
template<int MODE>
__global__ __launch_bounds__(256) void k_gemm(const _Float16* __restrict__ A,
    const _Float16* __restrict__ Bw, _Float16* __restrict__ oh,
    float* __restrict__ of, int ldc, int ntn, int nwg){
  __shared__ __align__(16) _Float16 As[3][128*32];   // 3 x 8 KB
  __shared__ __align__(16) _Float16 Bs[3][128*32];
  const int orig = blockIdx.x;
  const int xcd = orig & 7, slot = orig >> 3;
  const int q8 = nwg >> 3, r8 = nwg & 7;
  const int base = (xcd < r8) ? xcd*(q8+1) : r8*(q8+1) + (xcd-r8)*q8;
  const int lin = base + slot;
  const int m0 = (lin / ntn) * 128, n0 = (lin % ntn) * 128;
  const int t = threadIdx.x, lane = t & 63;
  const int wid = t >> 6, wm = (wid>>1)*64, wn = (wid&1)*64;
  const int lr = lane & 15, kg = lane >> 4;
  const _Float16* Ab = A  + (size_t)m0*512;
  const _Float16* Bb = Bw + (size_t)n0*512;
  const int foff0 = wid*64, foff1 = 256 + wid*64;
  const int f0 = foff0 + lane, f1 = foff1 + lane;
  const int r0 = f0 >> 2, r1 = f1 >> 2;
  const size_t ga0 = (size_t)r0*512 + ((f0&3) ^ ((r0>>1)&3))*8;
  const size_t ga1 = (size_t)r1*512 + ((f1&3) ^ ((r1>>1)&3))*8;
  const int swz = (lr>>1) & 3;           // read-side XOR (row bits 1-2)

  auto STAGE = [&](int buf, int kt){
    const int k0 = kt*32;
    GLOAD16(Ab + ga0 + k0, &As[buf][foff0*8]);
    GLOAD16(Bb + ga0 + k0, &Bs[buf][foff0*8]);
    GLOAD16(Ab + ga1 + k0, &As[buf][foff1*8]);
    GLOAD16(Bb + ga1 + k0, &Bs[buf][foff1*8]);
  };
  STAGE(0, 0);
  STAGE(1, 1);                            // 8 loads in flight

  f32x4 acc[4][4] = {};
  int buf = 0;
  for(int kt = 0; kt < 16; ++kt){
    if(kt + 2 < 16){
      int nb = buf + 2; if(nb >= 3) nb -= 3;
      STAGE(nb, kt + 2);                  // 12 in flight
    }
    if(kt < 14)       asm volatile("s_waitcnt vmcnt(8)" ::: "memory");
    else if(kt == 14) asm volatile("s_waitcnt vmcnt(4)" ::: "memory");
    else              asm volatile("s_waitcnt vmcnt(0)" ::: "memory");
    SCHEDB();
    __builtin_amdgcn_s_barrier();         // all waves' tile-kt loads landed
    SCHEDB();
    const _Float16* Ac = As[buf];
    const _Float16* Bc = Bs[buf];
    half8 af[4], bf[4];
    #pragma unroll
    for(int mt=0;mt<4;mt++)
      af[mt] = *(const half8*)&Ac[(wm + mt*16 + lr)*32 + (kg ^ swz)*8];
    #pragma unroll
    for(int nt=0;nt<4;nt++)
      bf[nt] = *(const half8*)&Bc[(wn + nt*16 + lr)*32 + (kg ^ swz)*8];
    #pragma unroll
    for(int mt=0;mt<4;mt++)
      #pragma unroll
      for(int nt=0;nt<4;nt++)
        acc[mt][nt] = MFMA16(af[mt], bf[nt], acc[mt][nt]);
    SCHEDB();
    __builtin_amdgcn_s_barrier();         // reads done -> buf may be restaged
    SCHEDB();
    buf += 1; if(buf >= 3) buf -= 3;
  }
  #pragma unroll
  for(int mt=0;mt<4;mt++)
    #pragma unroll
    for(int nt=0;nt<4;nt++)
      #pragma unroll
      for(int r=0;r<4;r++){
        int row = m0 + wm + mt*16 + kg*4 + r;
        int col = n0 + wn + nt*16 + lr;
        float vv = acc[mt][nt][r];
        if(MODE == 0){
          oh[(size_t)row*ldc + col] = (_Float16)vv;
        } else {
          if(row < MROWSQ) of[(size_t)row*ldc + col] = vv;
        }
      }
}

// ---- repack kv (row-major M x 1024) -> K head-major [w][h][j][dh]
//      and V TRANSPOSED [w][h][dh][j_pad32] (pad zeroed) ----
__global__ __launch_bounds__(256) void k_repack(const _Float16* __restrict__ kvb,
    _Float16* __restrict__ kb, _Float16* __restrict__ vb){
  __shared__ uint2 s2[6400];              // 25 rows x 256 uint2 = 50 KB
  uint32_t* su = (uint32_t*)s2;
  const int w = blockIdx.x, t = threadIdx.x;
  const uint2* src = (const uint2*)(kvb + (size_t)w*25*1024);
  #pragma unroll
  for(int it=0; it<25; ++it){
    int U = it*256 + t;
    int j = U >> 8, u = U & 255;          // u = dh*16 + (h>>1)
    s2[j*256 + (u ^ (u>>4) ^ (j&15))] = src[U];
  }
  __syncthreads();
  _Float16* kdst = kb + (size_t)w*12800;
  // K: [h][j][dh], unchanged
  for(int it=0; it<7; ++it){
    int q = it*256 + t;                   // half8 index into [32h][25j][2half]
    if(q < 1600){
      int h = q/50, rem = q%50, j = rem>>1, half = rem&1;
      half8 k8;
      #pragma unroll
      for(int jj=0;jj<8;jj++){
        int dh = half*8 + jj;
        int slot = j*256 + ((dh*16 + (h>>1)) ^ dh ^ (j&15));
        uint32_t val = su[slot*2 + (h&1)];
        k8[jj] = ((_Float16*)&val)[0];    // c=0 -> K
      }
      *(half8*)(kdst + q*8) = k8;
    }
  }
  // V^T: [h][dh][j32], j>=25 zero pad
  _Float16* vtdst = vb + (size_t)w*16384;
  for(int it=0; it<8; ++it){
    int u = it*256 + t;                   // half8 index into [32h][16dh][4jq]
    int h = u >> 6, rem = u & 63;
    int dh = rem >> 2, jq = rem & 3;
    half8 v8 = h8z();
    #pragma unroll
    for(int jj=0;jj<8;jj++){
      int j = jq*8 + jj;
      if(j < 25){
        int slot = j*256 + ((dh*16 + (h>>1)) ^ dh ^ (j&15));
        uint32_t val = su[slot*2 + (h&1)];
        v8[jj] = ((_Float16*)&val)[1];    // c=1 -> V
      }
    }
    *(half8*)(vtdst + u*8) = v8;
  }
}

// ---- attention: swapped QK^T (S^T = K x Q), softmax fully in-register ----
// grid (NW, 4), 256 threads (best measured config across 8 variants).
// Wave wv handles heads hA = hi*4+wv, hB = hA+16. V^T frags. No LDS.
__global__ __launch_bounds__(256) void k_attn(const _Float16* __restrict__ q,
    const _Float16* __restrict__ kb, const _Float16* __restrict__ vb,
    const float* __restrict__ biasT, _Float16* __restrict__ ao){
  const int w = blockIdx.x, hi = blockIdx.y, t = threadIdx.x;
  const int lane = t & 63, wv = t >> 6;
  const int lr = lane & 15, kg = lane >> 4;
  const size_t qbase = ((size_t)w*49)*512;
  const int hA = hi*4 + wv;              // 0..15
  const size_t kvA = (((size_t)w*32 + hA)*25)*16;
  const size_t kvB = kvA + 6400;         // +16 heads (K layout)
  half8 kA0=h8z(), kA1=h8z(), kB0=h8z(), kB1=h8z();
  if(kg < 2){
    kA0 = *(const half8*)(kb + kvA + lr*16 + kg*8);
    kB0 = *(const half8*)(kb + kvB + lr*16 + kg*8);
    if(lr < 9){
      kA1 = *(const half8*)(kb + kvA + (16+lr)*16 + kg*8);
      kB1 = *(const half8*)(kb + kvB + (16+lr)*16 + kg*8);
    }
  }
  half8 qA[4], qB[4];
  #pragma unroll
  for(int qt=0;qt<4;qt++){
    if(kg < 2){
      const _Float16* p = q + qbase + (size_t)(qt*16+lr)*512 + hA*16 + kg*8;
      qA[qt] = *(const half8*)p;
      qB[qt] = *(const half8*)(p + 256);
    } else { qA[qt] = h8z(); qB[qt] = h8z(); }
  }
  // V frags from V^T [h][dh=lr][j32]: keys {kg*4..+3} and {16+kg*4..+3}
  half8 vA, vB;
  {
    const _Float16* vtA = vb + ((size_t)w*32 + hA)*512 + lr*32 + kg*4;
    const _Float16* vtB = vtA + 16*512;   // +16 heads (V^T layout)
    half4 a0 = *(const half4*)vtA;
    half4 a1 = *(const half4*)(vtA + 16);
    half4 b0 = *(const half4*)vtB;
    half4 b1 = *(const half4*)(vtB + 16);
    vA = __builtin_shufflevector(a0, a1, 0,1,2,3,4,5,6,7);
    vB = __builtin_shufflevector(b0, b1, 0,1,2,3,4,5,6,7);
  }
  const float4* btA = (const float4*)(biasT + (size_t)hA*2048);
  const float4* btB = (const float4*)(biasT + (size_t)(hA+16)*2048);
  #pragma unroll
  for(int qt=0;qt<4;qt++){
    f32x4 sA0={}, sA1={}, sB0={}, sB1={};
    sA0 = MFMA16(kA0, qA[qt], sA0);      // S^T[key][query]
    sA1 = MFMA16(kA1, qA[qt], sA1);
    sB0 = MFMA16(kB0, qB[qt], sB0);
    sB1 = MFMA16(kB1, qB[qt], sB1);
    const int i = qt*16 + lr;            // this lane's query
    const int bidx = i*8 + kg*2;         // float4 units
    float4 bA0 = btA[bidx], bA1 = btA[bidx+1];
    float4 bB0 = btB[bidx], bB1 = btB[bidx+1];
    float a[8], b[8];
    a[0]=sA0[0]+bA0.x; a[1]=sA0[1]+bA0.y; a[2]=sA0[2]+bA0.z; a[3]=sA0[3]+bA0.w;
    a[4]=sA1[0]+bA1.x; a[5]=sA1[1]+bA1.y; a[6]=sA1[2]+bA1.z; a[7]=sA1[3]+bA1.w;
    b[0]=sB0[0]+bB0.x; b[1]=sB0[1]+bB0.y; b[2]=sB0[2]+bB0.z; b[3]=sB0[3]+bB0.w;
    b[4]=sB1[0]+bB1.x; b[5]=sB1[1]+bB1.y; b[6]=sB1[2]+bB1.z; b[7]=sB1[3]+bB1.w;
    float mA = a[0], mB = b[0];
    #pragma unroll
    for(int j=1;j<8;j++){ mA = fmaxf(mA, a[j]); mB = fmaxf(mB, b[j]); }
    mA = fmaxf(mA, __shfl_xor(mA,16)); mB = fmaxf(mB, __shfl_xor(mB,16));
    mA = fmaxf(mA, __shfl_xor(mA,32)); mB = fmaxf(mB, __shfl_xor(mB,32));
    float sumA = 0.f, sumB = 0.f;
    #pragma unroll
    for(int j=0;j<8;j++){
      a[j] = exp2f(a[j]-mA); sumA += a[j];
      b[j] = exp2f(b[j]-mB); sumB += b[j];
    }
    sumA += __shfl_xor(sumA,16); sumB += __shfl_xor(sumB,16);
    sumA += __shfl_xor(sumA,32); sumB += __shfl_xor(sumB,32);
    float invA = 1.f/sumA, invB = 1.f/sumB;
    half8 pA, pB;
    #pragma unroll
    for(int j=0;j<8;j++){
      pA[j] = (_Float16)(a[j]*invA);
      pB[j] = (_Float16)(b[j]*invB);
    }
    f32x4 oA={}, oB={};
    oA = MFMA16(pA, vA, oA);             // O[query][dh]
    oB = MFMA16(pB, vB, oB);
    #pragma unroll
    for(int r=0;r<4;r++){
      int qi2 = qt*16 + kg*4 + r;
      if(qi2 < 49){
        _Float16* dst = ao + qbase + (size_t)qi2*512 + hA*16 + lr;
        dst[0]   = (_Float16)oA[r];
        dst[256] = (_Float16)oB[r];
      }
    }
  }
}

extern "C" void kernel_launch(void* const* d_in, const int* in_sizes, int n_in,
                              void* d_out, int out_size, void* d_ws, size_t ws_size,
                              hipStream_t stream){
  (void)in_sizes; (void)n_in; (void)out_size; (void)ws_size;
  const float* x    = (const float*)d_in[0];
  const float* gam  = (const float*)d_in[1];
  const float* bet  = (const float*)d_in[2];
  const float* Wq   = (const float*)d_in[3];
  const float* Wkv  = (const float*)d_in[4];
  const float* Wout = (const float*)d_in[5];
  const float* rel  = (const float*)d_in[6];
  float* out = (float*)d_out;

  char* ws = (char*)d_ws;
  size_t off = 0;
  auto alloc = [&](size_t n){ char* p = ws + off; off += (n + 1023) & ~(size_t)1023; return p; };
  _Float16* xn    = (_Float16*)alloc((size_t)MPADQ*512*2);      // also reused as attn_out
  _Float16* xkv   = (_Float16*)alloc((size_t)MPADKV*512*2);
  _Float16* kvb   = (_Float16*)alloc((size_t)MPADKV*1024*2);    // later reused as qb
  _Float16* kbuf  = (_Float16*)alloc((size_t)NW*32*25*16*2);
  _Float16* vbuf  = (_Float16*)alloc((size_t)NW*32*16*32*2);    // V^T, j padded to 32
  _Float16* wqh   = (_Float16*)alloc((size_t)262144*2);
  _Float16* wkvh  = (_Float16*)alloc((size_t)524288*2);
  _Float16* wouth = (_Float16*)alloc((size_t)262144*2);
  float*    biasT = (float*)   alloc((size_t)65536*4);          // [32][64][4][8]
  _Float16* qb    = kvb;   // alias: kvb dead after k_repack, qb written after

  k_prep_w   <<<dim3(4096), 256, 0, stream>>>(Wq, Wkv, Wout, wqh, wkvh, wouth);
  k_prep_bias<<<dim3(256),  256, 0, stream>>>(rel, biasT);
  k_ln       <<<dim3(19208),256, 0, stream>>>(x, gam, bet, xn);
  k_pool     <<<dim3(9800), 256, 0, stream>>>(xn, gam, bet, xkv);
  k_gemm<0>  <<<dim3(2456), 256, 0, stream>>>(xkv, wkvh, kvb, nullptr, 1024, 8, 2456);
  k_repack   <<<dim3(NW),   256, 0, stream>>>(kvb, kbuf, vbuf);
  k_gemm<0>  <<<dim3(2404), 256, 0, stream>>>(xn,  wqh,  qb,  nullptr,  512, 4, 2404);
  k_attn     <<<dim3(NW,4), 256, 0, stream>>>(qb, kbuf, vbuf, biasT, xn);
  k_gemm<1>  <<<dim3(2404), 256, 0, stream>>>(xn,  wouth, nullptr, out, 512, 4, 2404);
}